// Round 1
// baseline (310.081 us; speedup 1.0000x reference)
//
#include <hip/hip_runtime.h>
#include <hip/hip_bf16.h>

// Problem constants
#define NN     8192      // nodes
#define D0     512       // x feature dim
#define D1     256       // hidden dim (W1 out)
#define D2     64        // z dim (W2 out)
#define NE     262144    // edges

// ---------------------------------------------------------------------------
// GEMM1: xw1[8192][256] = x[8192][512] @ W1[512][256]   (fp32, tiled)
// BM=64, BN=64, BK=32, 256 threads, 4x4 micro-tile
// ---------------------------------------------------------------------------
#define G1_BM 64
#define G1_BN 64
#define G1_BK 32

__global__ __launch_bounds__(256) void gemm_xw1_k(const float* __restrict__ X,
                                                  const float* __restrict__ W,
                                                  float* __restrict__ O) {
    __shared__ __align__(16) float As[G1_BK][G1_BM + 4];  // [k][m], stride 68 floats = 272B (16B aligned)
    __shared__ __align__(16) float Bs[G1_BK][G1_BN + 4];
    const int tid = threadIdx.x;
    const int tx = tid & 15;          // 0..15 col group
    const int ty = tid >> 4;          // 0..15 row group
    const int rowBase = blockIdx.y * G1_BM;
    const int colBase = blockIdx.x * G1_BN;

    float acc[4][4] = {};

    for (int k0 = 0; k0 < D0; k0 += G1_BK) {
        // A tile: 64 rows x 32 k = 512 float4, 2 per thread (transposed store)
        #pragma unroll
        for (int l = 0; l < 2; ++l) {
            int f4 = tid + l * 256;
            int r  = f4 >> 3;         // 0..63
            int c4 = f4 & 7;          // 0..7
            float4 v = *reinterpret_cast<const float4*>(&X[(rowBase + r) * D0 + k0 + c4 * 4]);
            As[c4 * 4 + 0][r] = v.x;
            As[c4 * 4 + 1][r] = v.y;
            As[c4 * 4 + 2][r] = v.z;
            As[c4 * 4 + 3][r] = v.w;
        }
        // B tile: 32 k x 64 n = 512 float4, 2 per thread (natural layout)
        #pragma unroll
        for (int l = 0; l < 2; ++l) {
            int f4 = tid + l * 256;
            int r  = f4 >> 4;         // 0..31
            int c4 = f4 & 15;         // 0..15
            float4 v = *reinterpret_cast<const float4*>(&W[(k0 + r) * D1 + colBase + c4 * 4]);
            *reinterpret_cast<float4*>(&Bs[r][c4 * 4]) = v;
        }
        __syncthreads();
        #pragma unroll
        for (int kk = 0; kk < G1_BK; ++kk) {
            float4 av4 = *reinterpret_cast<const float4*>(&As[kk][ty * 4]);
            float4 bv4 = *reinterpret_cast<const float4*>(&Bs[kk][tx * 4]);
            float a[4] = {av4.x, av4.y, av4.z, av4.w};
            float b[4] = {bv4.x, bv4.y, bv4.z, bv4.w};
            #pragma unroll
            for (int i = 0; i < 4; ++i)
                #pragma unroll
                for (int j = 0; j < 4; ++j)
                    acc[i][j] += a[i] * b[j];
        }
        __syncthreads();
    }
    #pragma unroll
    for (int i = 0; i < 4; ++i) {
        float4 v = make_float4(acc[i][0], acc[i][1], acc[i][2], acc[i][3]);
        *reinterpret_cast<float4*>(&O[(rowBase + ty * 4 + i) * D1 + colBase + tx * 4]) = v;
    }
}

// ---------------------------------------------------------------------------
// CSR build: histogram -> exclusive scan -> scatter permutation
// ---------------------------------------------------------------------------
__global__ __launch_bounds__(256) void hist_k(const int* __restrict__ dst,
                                              int* __restrict__ counts) {
    int i = blockIdx.x * 256 + threadIdx.x;
    if (i < NE) atomicAdd(&counts[dst[i]], 1);
}

__global__ __launch_bounds__(1024) void scan_k(const int* __restrict__ counts,
                                               int* __restrict__ rs) {
    __shared__ int part[1024];
    const int tid = threadIdx.x;
    const int base = tid * 8;
    int v[8];
    int s = 0;
    #pragma unroll
    for (int j = 0; j < 8; ++j) { v[j] = counts[base + j]; s += v[j]; }
    part[tid] = s;
    __syncthreads();
    // Hillis-Steele inclusive scan over 1024 partials
    for (int off = 1; off < 1024; off <<= 1) {
        int x = (tid >= off) ? part[tid - off] : 0;
        __syncthreads();
        part[tid] += x;
        __syncthreads();
    }
    int ex = (tid == 0) ? 0 : part[tid - 1];
    #pragma unroll
    for (int j = 0; j < 8; ++j) { rs[base + j] = ex; ex += v[j]; }
    if (tid == 1023) rs[NN] = ex;
}

__global__ __launch_bounds__(256) void scatter_k(const int* __restrict__ src,
                                                 const int* __restrict__ dst,
                                                 const float* __restrict__ w,
                                                 const int* __restrict__ rs,
                                                 int* __restrict__ cursor,
                                                 int* __restrict__ eps,
                                                 float* __restrict__ epw) {
    int i = blockIdx.x * 256 + threadIdx.x;
    if (i < NE) {
        int d = dst[i];
        int pos = rs[d] + atomicAdd(&cursor[d], 1);
        eps[pos] = src[i];
        epw[pos] = w[i];
    }
}

// ---------------------------------------------------------------------------
// SPMM layer 1 + relu: h1[row][c] = relu( sum_e w_e * xw1[src_e][c] ), 256 cols
// one block (256 threads) per dst row
// ---------------------------------------------------------------------------
__global__ __launch_bounds__(256) void spmm_relu_k(const float* __restrict__ Hin,
                                                   const int* __restrict__ rs,
                                                   const int* __restrict__ eps,
                                                   const float* __restrict__ epw,
                                                   float* __restrict__ Hout) {
    const int row = blockIdx.x;
    const int tid = threadIdx.x;
    const int start = rs[row], end = rs[row + 1];
    float acc = 0.f;
    for (int j = start; j < end; ++j) {
        int s = eps[j];
        float w = epw[j];
        acc += w * Hin[s * D1 + tid];
    }
    Hout[row * D1 + tid] = fmaxf(acc, 0.f);
}

// ---------------------------------------------------------------------------
// GEMM2: h1w2[8192][64] = h1[8192][256] @ W2[256][64]
// 4 rows per 256-thread block; h1 rows staged in LDS
// ---------------------------------------------------------------------------
__global__ __launch_bounds__(256) void gemm_h1w2_k(const float* __restrict__ H,
                                                   const float* __restrict__ W,
                                                   float* __restrict__ O) {
    __shared__ __align__(16) float hs[4][D1];
    const int tid = threadIdx.x;
    const int r = tid >> 6;   // 0..3
    const int c = tid & 63;   // 0..63
    const int row0 = blockIdx.x * 4;
    // load 4 rows x 256 cols = 256 float4, one per thread
    {
        int lr = tid >> 6, lc4 = tid & 63;
        *reinterpret_cast<float4*>(&hs[lr][lc4 * 4]) =
            *reinterpret_cast<const float4*>(&H[(row0 + lr) * D1 + lc4 * 4]);
    }
    __syncthreads();
    float acc = 0.f;
    #pragma unroll 8
    for (int k = 0; k < D1; ++k) acc += hs[r][k] * W[k * D2 + c];
    O[(row0 + r) * D2 + c] = acc;
}

// ---------------------------------------------------------------------------
// SPMM layer 2: z[row][c] = sum_e w_e * h1w2[src_e][c], 64 cols
// 4 rows per 256-thread block (one wave per row — wave-uniform loop bounds)
// ---------------------------------------------------------------------------
__global__ __launch_bounds__(256) void spmm64_k(const float* __restrict__ Hin,
                                                const int* __restrict__ rs,
                                                const int* __restrict__ eps,
                                                const float* __restrict__ epw,
                                                float* __restrict__ Z) {
    const int row = blockIdx.x * 4 + (threadIdx.x >> 6);
    const int c = threadIdx.x & 63;
    const int start = rs[row], end = rs[row + 1];
    float acc = 0.f;
    for (int j = start; j < end; ++j) {
        acc += epw[j] * Hin[eps[j] * D2 + c];
    }
    Z[row * D2 + c] = acc;
}

// ---------------------------------------------------------------------------
// ZZT: out[8192][8192] = z @ z^T, z[8192][64] fp32.
// BM=BN=128, K=64 (single chunk), 256 threads, 8x8 micro-tile.
// LDS: As/Bs stored [k][m] (transposed), 64x128 each = exactly 64KB total.
// Column split (tx*4 and 64+tx*4) keeps b128 LDS reads at 2-way (free) aliasing.
// ---------------------------------------------------------------------------
#define Z_BM 128

__global__ __launch_bounds__(256) void zzt_k(const float* __restrict__ Zm,
                                             float* __restrict__ O) {
    __shared__ __align__(16) float As[D2][Z_BM];
    __shared__ __align__(16) float Bs[D2][Z_BM];
    const int tid = threadIdx.x;
    const int tx = tid & 15;   // 0..15
    const int ty = tid >> 4;   // 0..15
    const int rowBase = blockIdx.y * Z_BM;
    const int colBase = blockIdx.x * Z_BM;

    // load both tiles: 128 rows x 64 cols each = 2048 float4, 8 per thread
    #pragma unroll
    for (int l = 0; l < 8; ++l) {
        int f4 = tid + l * 256;
        int r  = f4 >> 4;      // 0..127
        int c4 = f4 & 15;      // 0..15
        float4 v = *reinterpret_cast<const float4*>(&Zm[(rowBase + r) * D2 + c4 * 4]);
        As[c4 * 4 + 0][r] = v.x;
        As[c4 * 4 + 1][r] = v.y;
        As[c4 * 4 + 2][r] = v.z;
        As[c4 * 4 + 3][r] = v.w;
        float4 u = *reinterpret_cast<const float4*>(&Zm[(colBase + r) * D2 + c4 * 4]);
        Bs[c4 * 4 + 0][r] = u.x;
        Bs[c4 * 4 + 1][r] = u.y;
        Bs[c4 * 4 + 2][r] = u.z;
        Bs[c4 * 4 + 3][r] = u.w;
    }
    __syncthreads();

    float acc[8][8] = {};
    #pragma unroll 8
    for (int kk = 0; kk < D2; ++kk) {
        float a[8], b[8];
        *reinterpret_cast<float4*>(&a[0]) = *reinterpret_cast<const float4*>(&As[kk][ty * 8]);
        *reinterpret_cast<float4*>(&a[4]) = *reinterpret_cast<const float4*>(&As[kk][ty * 8 + 4]);
        // column split: first 4 cols at tx*4, next 4 at 64 + tx*4
        *reinterpret_cast<float4*>(&b[0]) = *reinterpret_cast<const float4*>(&Bs[kk][tx * 4]);
        *reinterpret_cast<float4*>(&b[4]) = *reinterpret_cast<const float4*>(&Bs[kk][64 + tx * 4]);
        #pragma unroll
        for (int i = 0; i < 8; ++i)
            #pragma unroll
            for (int j = 0; j < 8; ++j)
                acc[i][j] += a[i] * b[j];
    }

    #pragma unroll
    for (int i = 0; i < 8; ++i) {
        int orow = rowBase + ty * 8 + i;
        float4 v0 = make_float4(acc[i][0], acc[i][1], acc[i][2], acc[i][3]);
        float4 v1 = make_float4(acc[i][4], acc[i][5], acc[i][6], acc[i][7]);
        *reinterpret_cast<float4*>(&O[orow * NN + colBase + tx * 4]) = v0;
        *reinterpret_cast<float4*>(&O[orow * NN + colBase + 64 + tx * 4]) = v1;
    }
}

// ---------------------------------------------------------------------------
// Launch
// ---------------------------------------------------------------------------
extern "C" void kernel_launch(void* const* d_in, const int* in_sizes, int n_in,
                              void* d_out, int out_size, void* d_ws, size_t ws_size,
                              hipStream_t stream) {
    const float* x        = (const float*)d_in[0];
    const int*   edge_src = (const int*)d_in[1];
    const int*   edge_dst = (const int*)d_in[2];
    const float* edge_w   = (const float*)d_in[3];
    const float* W1       = (const float*)d_in[4];
    const float* W2       = (const float*)d_in[5];
    float* out = (float*)d_out;

    char* ws = (char*)d_ws;
    // workspace layout (bytes)
    const size_t OFF_XW1  = 0;                          // 8192*256*4  = 8,388,608
    const size_t OFF_H1   = OFF_XW1  + (size_t)NN * D1 * 4;
    const size_t OFF_H1W2 = OFF_H1   + (size_t)NN * D1 * 4;   // 2,097,152
    const size_t OFF_Z    = OFF_H1W2 + (size_t)NN * D2 * 4;
    const size_t OFF_RS   = OFF_Z    + (size_t)NN * D2 * 4;   // (NN+1) ints
    const size_t OFF_CNT  = OFF_RS   + 33280;                 // NN ints
    const size_t OFF_CUR  = OFF_CNT  + (size_t)NN * 4;        // NN ints
    const size_t OFF_EPS  = OFF_CUR  + (size_t)NN * 4;        // NE ints
    const size_t OFF_EPW  = OFF_EPS  + (size_t)NE * 4;        // NE floats

    float* xw1  = (float*)(ws + OFF_XW1);
    float* h1   = (float*)(ws + OFF_H1);
    float* h1w2 = (float*)(ws + OFF_H1W2);
    float* z    = (float*)(ws + OFF_Z);
    int*   rs   = (int*)(ws + OFF_RS);
    int*   cnt  = (int*)(ws + OFF_CNT);
    int*   cur  = (int*)(ws + OFF_CUR);
    int*   eps  = (int*)(ws + OFF_EPS);
    float* epw  = (float*)(ws + OFF_EPW);

    // zero counts + cursor (adjacent, 64KB total)
    hipMemsetAsync(cnt, 0, (size_t)NN * 4 * 2, stream);

    // GEMM1: xw1 = x @ W1
    gemm_xw1_k<<<dim3(D1 / G1_BN, NN / G1_BM), 256, 0, stream>>>(x, W1, xw1);

    // CSR build
    hist_k<<<NE / 256, 256, 0, stream>>>(edge_dst, cnt);
    scan_k<<<1, 1024, 0, stream>>>(cnt, rs);
    scatter_k<<<NE / 256, 256, 0, stream>>>(edge_src, edge_dst, edge_w, rs, cur, eps, epw);

    // SPMM1 + relu
    spmm_relu_k<<<NN, 256, 0, stream>>>(xw1, rs, eps, epw, h1);

    // GEMM2: h1w2 = h1 @ W2
    gemm_h1w2_k<<<NN / 4, 256, 0, stream>>>(h1, W2, h1w2);

    // SPMM2
    spmm64_k<<<NN / 4, 256, 0, stream>>>(h1w2, rs, eps, epw, z);

    // recon = z @ z^T
    zzt_k<<<dim3(NN / Z_BM, NN / Z_BM), 256, 0, stream>>>(z, out);
}

// Round 2
// 246.600 us; speedup vs baseline: 1.2574x; 1.2574x over previous
//
#include <hip/hip_runtime.h>
#include <hip/hip_bf16.h>

// Problem constants
#define NN     8192      // nodes
#define D0     512       // x feature dim
#define D1     256       // hidden dim (W1 out)
#define D2     64        // z dim (W2 out)
#define NE     262144    // edges

typedef __attribute__((ext_vector_type(8)))  __bf16 bf16x8;
typedef __attribute__((ext_vector_type(16))) float  f32x16;

// ---------------------------------------------------------------------------
// GEMM1: xw1[8192][256] = x[8192][512] @ W1[512][256]   (fp32, tiled)
// ---------------------------------------------------------------------------
#define G1_BM 64
#define G1_BN 64
#define G1_BK 32

__global__ __launch_bounds__(256) void gemm_xw1_k(const float* __restrict__ X,
                                                  const float* __restrict__ W,
                                                  float* __restrict__ O) {
    __shared__ __align__(16) float As[G1_BK][G1_BM + 4];
    __shared__ __align__(16) float Bs[G1_BK][G1_BN + 4];
    const int tid = threadIdx.x;
    const int tx = tid & 15;
    const int ty = tid >> 4;
    const int rowBase = blockIdx.y * G1_BM;
    const int colBase = blockIdx.x * G1_BN;

    float acc[4][4] = {};

    for (int k0 = 0; k0 < D0; k0 += G1_BK) {
        #pragma unroll
        for (int l = 0; l < 2; ++l) {
            int f4 = tid + l * 256;
            int r  = f4 >> 3;
            int c4 = f4 & 7;
            float4 v = *reinterpret_cast<const float4*>(&X[(rowBase + r) * D0 + k0 + c4 * 4]);
            As[c4 * 4 + 0][r] = v.x;
            As[c4 * 4 + 1][r] = v.y;
            As[c4 * 4 + 2][r] = v.z;
            As[c4 * 4 + 3][r] = v.w;
        }
        #pragma unroll
        for (int l = 0; l < 2; ++l) {
            int f4 = tid + l * 256;
            int r  = f4 >> 4;
            int c4 = f4 & 15;
            float4 v = *reinterpret_cast<const float4*>(&W[(k0 + r) * D1 + colBase + c4 * 4]);
            *reinterpret_cast<float4*>(&Bs[r][c4 * 4]) = v;
        }
        __syncthreads();
        #pragma unroll
        for (int kk = 0; kk < G1_BK; ++kk) {
            float4 av4 = *reinterpret_cast<const float4*>(&As[kk][ty * 4]);
            float4 bv4 = *reinterpret_cast<const float4*>(&Bs[kk][tx * 4]);
            float a[4] = {av4.x, av4.y, av4.z, av4.w};
            float b[4] = {bv4.x, bv4.y, bv4.z, bv4.w};
            #pragma unroll
            for (int i = 0; i < 4; ++i)
                #pragma unroll
                for (int j = 0; j < 4; ++j)
                    acc[i][j] += a[i] * b[j];
        }
        __syncthreads();
    }
    #pragma unroll
    for (int i = 0; i < 4; ++i) {
        float4 v = make_float4(acc[i][0], acc[i][1], acc[i][2], acc[i][3]);
        *reinterpret_cast<float4*>(&O[(rowBase + ty * 4 + i) * D1 + colBase + tx * 4]) = v;
    }
}

// ---------------------------------------------------------------------------
// zero cnt+cur (replaces pathological in-graph rocclr fill): 4096 x int4 = 64KB
// ---------------------------------------------------------------------------
__global__ __launch_bounds__(256) void zero_k(int4* __restrict__ p) {
    p[blockIdx.x * 256 + threadIdx.x] = make_int4(0, 0, 0, 0);
}

// ---------------------------------------------------------------------------
// CSR build
// ---------------------------------------------------------------------------
__global__ __launch_bounds__(256) void hist_k(const int* __restrict__ dst,
                                              int* __restrict__ counts) {
    int i = blockIdx.x * 256 + threadIdx.x;
    if (i < NE) atomicAdd(&counts[dst[i]], 1);
}

__global__ __launch_bounds__(1024) void scan_k(const int* __restrict__ counts,
                                               int* __restrict__ rs) {
    __shared__ int part[1024];
    const int tid = threadIdx.x;
    const int base = tid * 8;
    int v[8];
    int s = 0;
    #pragma unroll
    for (int j = 0; j < 8; ++j) { v[j] = counts[base + j]; s += v[j]; }
    part[tid] = s;
    __syncthreads();
    for (int off = 1; off < 1024; off <<= 1) {
        int x = (tid >= off) ? part[tid - off] : 0;
        __syncthreads();
        part[tid] += x;
        __syncthreads();
    }
    int ex = (tid == 0) ? 0 : part[tid - 1];
    #pragma unroll
    for (int j = 0; j < 8; ++j) { rs[base + j] = ex; ex += v[j]; }
    if (tid == 1023) rs[NN] = ex;
}

__global__ __launch_bounds__(256) void scatter_k(const int* __restrict__ src,
                                                 const int* __restrict__ dst,
                                                 const float* __restrict__ w,
                                                 const int* __restrict__ rs,
                                                 int* __restrict__ cursor,
                                                 int* __restrict__ eps,
                                                 float* __restrict__ epw) {
    int i = blockIdx.x * 256 + threadIdx.x;
    if (i < NE) {
        int d = dst[i];
        int pos = rs[d] + atomicAdd(&cursor[d], 1);
        eps[pos] = src[i];
        epw[pos] = w[i];
    }
}

// ---------------------------------------------------------------------------
// SPMM layer 1 + relu
// ---------------------------------------------------------------------------
__global__ __launch_bounds__(256) void spmm_relu_k(const float* __restrict__ Hin,
                                                   const int* __restrict__ rs,
                                                   const int* __restrict__ eps,
                                                   const float* __restrict__ epw,
                                                   float* __restrict__ Hout) {
    const int row = blockIdx.x;
    const int tid = threadIdx.x;
    const int start = rs[row], end = rs[row + 1];
    float acc = 0.f;
    for (int j = start; j < end; ++j) {
        int s = eps[j];
        float w = epw[j];
        acc += w * Hin[s * D1 + tid];
    }
    Hout[row * D1 + tid] = fmaxf(acc, 0.f);
}

// ---------------------------------------------------------------------------
// GEMM2: h1w2 = h1 @ W2
// ---------------------------------------------------------------------------
__global__ __launch_bounds__(256) void gemm_h1w2_k(const float* __restrict__ H,
                                                   const float* __restrict__ W,
                                                   float* __restrict__ O) {
    __shared__ __align__(16) float hs[4][D1];
    const int tid = threadIdx.x;
    const int r = tid >> 6;
    const int c = tid & 63;
    const int row0 = blockIdx.x * 4;
    {
        int lr = tid >> 6, lc4 = tid & 63;
        *reinterpret_cast<float4*>(&hs[lr][lc4 * 4]) =
            *reinterpret_cast<const float4*>(&H[(row0 + lr) * D1 + lc4 * 4]);
    }
    __syncthreads();
    float acc = 0.f;
    #pragma unroll 8
    for (int k = 0; k < D1; ++k) acc += hs[r][k] * W[k * D2 + c];
    O[(row0 + r) * D2 + c] = acc;
}

// ---------------------------------------------------------------------------
// SPMM layer 2: emits z split into hi/lo bf16 directly.
// z = zh + zl, zh = bf16(z), zl = bf16(z - float(zh))
// ---------------------------------------------------------------------------
__global__ __launch_bounds__(256) void spmm64_k(const float* __restrict__ Hin,
                                                const int* __restrict__ rs,
                                                const int* __restrict__ eps,
                                                const float* __restrict__ epw,
                                                __bf16* __restrict__ Zh,
                                                __bf16* __restrict__ Zl) {
    const int row = blockIdx.x * 4 + (threadIdx.x >> 6);
    const int c = threadIdx.x & 63;
    const int start = rs[row], end = rs[row + 1];
    float acc = 0.f;
    for (int j = start; j < end; ++j) {
        acc += epw[j] * Hin[eps[j] * D2 + c];
    }
    __bf16 h = (__bf16)acc;
    Zh[row * D2 + c] = h;
    Zl[row * D2 + c] = (__bf16)(acc - (float)h);
}

// ---------------------------------------------------------------------------
// ZZT via bf16 MFMA with hi/lo split:
//   out = zh@zh^T + zh@zl^T + zl@zh^T   (zl@zl dropped, ~2^-18 relative)
// Block = 128x128 tile, 4 waves in 2x2, each wave 64x64 = 2x2 frags of
// mfma_f32_32x32x16_bf16. No LDS: zh/zl are 2MB total, L2-resident; both
// A and B fragments are contiguous 16B row-loads (B = z^T => lane reads
// z[col][k..k+7]).
// A-frag: lane holds A[lane&31][kk*16 + (lane>>5)*8 + e], e=0..7
// B-frag: lane holds B[kk*16 + (lane>>5)*8 + e][lane&31] = z[col][k...]
// C/D:    col=lane&31, row=(reg&3)+8*(reg>>2)+4*(lane>>5)
// ---------------------------------------------------------------------------
__global__ __launch_bounds__(256) void zzt_k(const __bf16* __restrict__ Zh,
                                             const __bf16* __restrict__ Zl,
                                             float* __restrict__ O) {
    const int tid  = threadIdx.x;
    const int lane = tid & 63;
    const int w    = tid >> 6;        // wave 0..3
    const int wm   = w >> 1;          // 0..1
    const int wn   = w & 1;           // 0..1
    const int r32  = lane & 31;
    const int kh   = lane >> 5;       // k-half select
    const int rowBase = blockIdx.y * 128 + wm * 64;
    const int colBase = blockIdx.x * 128 + wn * 64;

    f32x16 acc[2][2] = {};

    #pragma unroll
    for (int kk = 0; kk < 4; ++kk) {
        const int koff = kk * 16 + kh * 8;
        bf16x8 ah0 = *reinterpret_cast<const bf16x8*>(&Zh[(rowBase +      r32) * D2 + koff]);
        bf16x8 ah1 = *reinterpret_cast<const bf16x8*>(&Zh[(rowBase + 32 + r32) * D2 + koff]);
        bf16x8 al0 = *reinterpret_cast<const bf16x8*>(&Zl[(rowBase +      r32) * D2 + koff]);
        bf16x8 al1 = *reinterpret_cast<const bf16x8*>(&Zl[(rowBase + 32 + r32) * D2 + koff]);
        bf16x8 bh0 = *reinterpret_cast<const bf16x8*>(&Zh[(colBase +      r32) * D2 + koff]);
        bf16x8 bh1 = *reinterpret_cast<const bf16x8*>(&Zh[(colBase + 32 + r32) * D2 + koff]);
        bf16x8 bl0 = *reinterpret_cast<const bf16x8*>(&Zl[(colBase +      r32) * D2 + koff]);
        bf16x8 bl1 = *reinterpret_cast<const bf16x8*>(&Zl[(colBase + 32 + r32) * D2 + koff]);

        acc[0][0] = __builtin_amdgcn_mfma_f32_32x32x16_bf16(ah0, bh0, acc[0][0], 0, 0, 0);
        acc[0][1] = __builtin_amdgcn_mfma_f32_32x32x16_bf16(ah0, bh1, acc[0][1], 0, 0, 0);
        acc[1][0] = __builtin_amdgcn_mfma_f32_32x32x16_bf16(ah1, bh0, acc[1][0], 0, 0, 0);
        acc[1][1] = __builtin_amdgcn_mfma_f32_32x32x16_bf16(ah1, bh1, acc[1][1], 0, 0, 0);

        acc[0][0] = __builtin_amdgcn_mfma_f32_32x32x16_bf16(ah0, bl0, acc[0][0], 0, 0, 0);
        acc[0][1] = __builtin_amdgcn_mfma_f32_32x32x16_bf16(ah0, bl1, acc[0][1], 0, 0, 0);
        acc[1][0] = __builtin_amdgcn_mfma_f32_32x32x16_bf16(ah1, bl0, acc[1][0], 0, 0, 0);
        acc[1][1] = __builtin_amdgcn_mfma_f32_32x32x16_bf16(ah1, bl1, acc[1][1], 0, 0, 0);

        acc[0][0] = __builtin_amdgcn_mfma_f32_32x32x16_bf16(al0, bh0, acc[0][0], 0, 0, 0);
        acc[0][1] = __builtin_amdgcn_mfma_f32_32x32x16_bf16(al0, bh1, acc[0][1], 0, 0, 0);
        acc[1][0] = __builtin_amdgcn_mfma_f32_32x32x16_bf16(al1, bh0, acc[1][0], 0, 0, 0);
        acc[1][1] = __builtin_amdgcn_mfma_f32_32x32x16_bf16(al1, bh1, acc[1][1], 0, 0, 0);
    }

    #pragma unroll
    for (int i = 0; i < 2; ++i)
        #pragma unroll
        for (int j = 0; j < 2; ++j)
            #pragma unroll
            for (int reg = 0; reg < 16; ++reg) {
                int r = (reg & 3) + 8 * (reg >> 2) + 4 * kh;
                O[(size_t)(rowBase + i * 32 + r) * NN + colBase + j * 32 + r32] = acc[i][j][reg];
            }
}

// ---------------------------------------------------------------------------
// Launch
// ---------------------------------------------------------------------------
extern "C" void kernel_launch(void* const* d_in, const int* in_sizes, int n_in,
                              void* d_out, int out_size, void* d_ws, size_t ws_size,
                              hipStream_t stream) {
    const float* x        = (const float*)d_in[0];
    const int*   edge_src = (const int*)d_in[1];
    const int*   edge_dst = (const int*)d_in[2];
    const float* edge_w   = (const float*)d_in[3];
    const float* W1       = (const float*)d_in[4];
    const float* W2       = (const float*)d_in[5];
    float* out = (float*)d_out;

    char* ws = (char*)d_ws;
    const size_t OFF_XW1  = 0;                                  // 8 MB
    const size_t OFF_H1   = OFF_XW1  + (size_t)NN * D1 * 4;     // 8 MB
    const size_t OFF_H1W2 = OFF_H1   + (size_t)NN * D1 * 4;     // 2 MB
    const size_t OFF_ZH   = OFF_H1W2 + (size_t)NN * D2 * 4;     // 1 MB
    const size_t OFF_ZL   = OFF_ZH   + (size_t)NN * D2 * 2;     // 1 MB
    const size_t OFF_RS   = OFF_ZL   + (size_t)NN * D2 * 2;     // (NN+1) ints
    const size_t OFF_CNT  = OFF_RS   + 33280;                   // NN ints
    const size_t OFF_CUR  = OFF_CNT  + (size_t)NN * 4;          // NN ints
    const size_t OFF_EPS  = OFF_CUR  + (size_t)NN * 4;          // NE ints
    const size_t OFF_EPW  = OFF_EPS  + (size_t)NE * 4;          // NE floats

    float*  xw1  = (float*)(ws + OFF_XW1);
    float*  h1   = (float*)(ws + OFF_H1);
    float*  h1w2 = (float*)(ws + OFF_H1W2);
    __bf16* zh   = (__bf16*)(ws + OFF_ZH);
    __bf16* zl   = (__bf16*)(ws + OFF_ZL);
    int*    rs   = (int*)(ws + OFF_RS);
    int*    cnt  = (int*)(ws + OFF_CNT);
    int*    cur  = (int*)(ws + OFF_CUR);
    int*    eps  = (int*)(ws + OFF_EPS);
    float*  epw  = (float*)(ws + OFF_EPW);

    // zero counts + cursor (64KB) with our own kernel — the in-graph
    // hipMemsetAsync rocclr fill showed ~157us (!) in rocprof
    zero_k<<<16, 256, 0, stream>>>((int4*)cnt);

    gemm_xw1_k<<<dim3(D1 / G1_BN, NN / G1_BM), 256, 0, stream>>>(x, W1, xw1);

    hist_k<<<NE / 256, 256, 0, stream>>>(edge_dst, cnt);
    scan_k<<<1, 1024, 0, stream>>>(cnt, rs);
    scatter_k<<<NE / 256, 256, 0, stream>>>(edge_src, edge_dst, edge_w, rs, cur, eps, epw);

    spmm_relu_k<<<NN, 256, 0, stream>>>(xw1, rs, eps, epw, h1);

    gemm_h1w2_k<<<NN / 4, 256, 0, stream>>>(h1, W2, h1w2);

    spmm64_k<<<NN / 4, 256, 0, stream>>>(h1w2, rs, eps, epw, zh, zl);

    zzt_k<<<dim3(NN / 128, NN / 128), 256, 0, stream>>>(zh, zl, out);
}